// Round 12
// baseline (614.143 us; speedup 1.0000x reference)
//
#include <hip/hip_runtime.h>
#include <stdint.h>

#define E_       8
#define D_       1024
#define DFFN_    2048
#define T_       8192
#define TK_      16384
#define CAP_     16896
#define MAXT_    144       // max 128-row tiles

// workspace layout (bytes)
#define WS_SEL      0u          // TK_*4
#define WS_TOTALS   0x10200u    // [0]=total_padded [1]=nTiles
#define WS_TILES    0x11300u    // MAXT_*4
#define WS_ROWSRC   0x12000u    // (CAP_+64)*4
#define WS_XBF      0x23000u    // T_*1024*2 = 16777216
#define WS_W1T      (0x23000u + 34603008u)              // 16384*1024*2 = 33554432
#define WS_H        (0x23000u + 34603008u + 33554432u)  // 512*8*4 router histograms

typedef __bf16 bf16x8 __attribute__((ext_vector_type(8)));
typedef float  f32x4  __attribute__((ext_vector_type(4)));
typedef unsigned short u16x8 __attribute__((ext_vector_type(8)));

__device__ __forceinline__ unsigned short f2bf(float f) {
  __bf16 b = (__bf16)f;                       // compiler RNE cast (single HW op)
  union { __bf16 h; unsigned short u; } v; v.h = b;
  return v.u;
}

// ---- 1. fused: router (0..511, + per-block histogram) + w1conv (512..1535) ----
__global__ __launch_bounds__(256) void k_rw(const float* __restrict__ x,
                                            const float* __restrict__ wr,
                                            const float* __restrict__ w1,
                                            int* __restrict__ sel,
                                            int* __restrict__ h,
                                            unsigned short* __restrict__ xbf,
                                            unsigned short* __restrict__ w1t) {
  __shared__ __align__(16) unsigned char smem[34816];  // max(router 32.9KB, w1conv 34KB)
  int tid = threadIdx.x;
  int bx = blockIdx.x;

  if (bx < 512) {
    // ---------- router: top-2 expert ids + bf16 cast of x + 32-entry histogram ----------
    float* lwr = (float*)smem;
    int* selL = (int*)(smem + 32768);    // 32 ints
    for (int i = tid; i < E_ * D_ / 4; i += 256)
      ((float4*)lwr)[i] = ((const float4*)wr)[i];
    __syncthreads();
    int wave = tid >> 6, lane = tid & 63;

    for (int tk = 0; tk < 4; ++tk) {
      int t = bx * 16 + wave * 4 + tk;
      double acc[E_];
#pragma unroll
      for (int e = 0; e < E_; ++e) acc[e] = 0.0;
      const float4* xr = (const float4*)(x + (size_t)t * D_);
      ushort4* xw = (ushort4*)(xbf + (size_t)t * D_);
#pragma unroll
      for (int j = 0; j < 4; ++j) {
        float4 v = xr[j * 64 + lane];
        ushort4 o;
        o.x = f2bf(v.x); o.y = f2bf(v.y); o.z = f2bf(v.z); o.w = f2bf(v.w);
        xw[j * 64 + lane] = o;
        int dbase = j * 256 + lane * 4;
#pragma unroll
        for (int e = 0; e < E_; ++e) {
          float4 w = *(const float4*)(lwr + e * D_ + dbase);
          acc[e] += (double)v.x * w.x + (double)v.y * w.y +
                    (double)v.z * w.z + (double)v.w * w.w;
        }
      }
#pragma unroll
      for (int e = 0; e < E_; ++e) {
        acc[e] += __shfl_xor(acc[e], 1, 64);
        acc[e] += __shfl_xor(acc[e], 2, 64);
        acc[e] += __shfl_xor(acc[e], 4, 64);
      }
      double s01 = (lane & 1) ? acc[1] : acc[0];
      double s23 = (lane & 1) ? acc[3] : acc[2];
      double s45 = (lane & 1) ? acc[5] : acc[4];
      double s67 = (lane & 1) ? acc[7] : acc[6];
      double t0 = (lane & 2) ? s23 : s01;
      double t1 = (lane & 2) ? s67 : s45;
      double u  = (lane & 4) ? t1 : t0;
      u += __shfl_xor(u, 8, 64);
      u += __shfl_xor(u, 16, 64);
      u += __shfl_xor(u, 32, 64);
      double lg[E_];
#pragma unroll
      for (int e = 0; e < E_; ++e) lg[e] = __shfl(u, e, 64);
      int e1 = 0; double b1 = lg[0];
#pragma unroll
      for (int e = 1; e < E_; ++e) if (lg[e] > b1) { b1 = lg[e]; e1 = e; }
      int e2 = (e1 == 0) ? 1 : 0; double b2 = lg[e2];
#pragma unroll
      for (int e = 0; e < E_; ++e) if (e != e1 && lg[e] > b2) { b2 = lg[e]; e2 = e; }
      if (lane == 0) {
        sel[2 * t]     = e1;
        sel[2 * t + 1] = e2;
        selL[wave * 8 + tk * 2]     = e1;
        selL[wave * 8 + tk * 2 + 1] = e2;
      }
    }
    __syncthreads();
    if (tid < E_) {
      int c = 0;
#pragma unroll
      for (int i = 0; i < 32; ++i) c += (selL[i] == tid);
      h[bx * E_ + tid] = c;
    }
  } else {
    // ---------- w1conv: 128d x 128n tile; 512B-contig reads, 256B-contig b128 writes ----------
    typedef unsigned short row136[136];
    row136* lds = (row136*)smem;
    int b = bx - 512;
    int n0 = (b & 127) * 128, d0 = (b >> 7) * 128;
    int rIn = tid >> 5, c4 = (tid & 31) * 4;
#pragma unroll
    for (int p = 0; p < 16; ++p) {
      int d = p * 8 + rIn;
      float4 v = *(const float4*)(w1 + (size_t)(d0 + d) * 16384 + n0 + c4);
      lds[d][c4 + 0] = f2bf(v.x);
      lds[d][c4 + 1] = f2bf(v.y);
      lds[d][c4 + 2] = f2bf(v.z);
      lds[d][c4 + 3] = f2bf(v.w);
    }
    __syncthreads();
    int nn = tid >> 3, d16 = (tid & 7) * 16;
#pragma unroll
    for (int q = 0; q < 4; ++q) {
      int n = q * 32 + nn;
      u16x8 o0, o1;
#pragma unroll
      for (int i = 0; i < 8; ++i) o0[i] = lds[d16 + i][n];
#pragma unroll
      for (int i = 0; i < 8; ++i) o1[i] = lds[d16 + 8 + i][n];
      unsigned short* dst = w1t + (size_t)(n0 + n) * 1024 + d0 + d16;
      *(u16x8*)dst = o0;
      *(u16x8*)(dst + 8) = o1;
    }
  }
}

// ---- 2. parallel placement (0..63 rank, 64 tile-table) + out-tail zero (65..576) ----
// tile word: bits0-14 rowBase | bits15-17 e | bit18 is128 | bits19-27 mValid
__global__ __launch_bounds__(256) void k_place(const int* __restrict__ sel,
                                               const int* __restrict__ h,
                                               int* __restrict__ totals,
                                               int* __restrict__ tiles,
                                               int* __restrict__ row_src,
                                               float* __restrict__ out) {
  int tid = threadIdx.x;
  int c = blockIdx.x;

  if (c >= 65) {
    // zero out rows [TK_, CAP_): gemm (launched after) overwrites valid ones
    int row = TK_ + (c - 65);
    float4 z = {0.f, 0.f, 0.f, 0.f};
    float4* o = (float4*)(out + (size_t)row * DFFN_);
    o[tid] = z;
    o[tid + 256] = z;
    return;
  }

  __shared__ int hL[512][8];     // router-block histograms
  __shared__ int preSC[64][8];   // exclusive prefix of 8-rb super-chunks per expert
  __shared__ int scnt[8];
  __shared__ int scum[9];

  // load h (16KB, coalesced)
  for (int i = tid; i < 512 * 8 / 4; i += 256)
    ((int4*)&hL[0][0])[i] = ((const int4*)h)[i];
  __syncthreads();

  // super-chunk sums
  for (int idx = tid; idx < 512; idx += 256) {
    int sc = idx >> 3, e = idx & 7;
    int s = 0;
#pragma unroll
    for (int i = 0; i < 8; ++i) s += hL[sc * 8 + i][e];
    preSC[sc][e] = s;
  }
  __syncthreads();

  // exclusive prefix over 64 super-chunks, per expert
  if (tid < 8) {
    int run = 0;
    for (int sc = 0; sc < 64; ++sc) {
      int v = preSC[sc][tid];
      preSC[sc][tid] = run;
      run += v;
    }
    scnt[tid] = run;
  }
  __syncthreads();
  if (tid == 0) {
    int cp = 0;
    scum[0] = 0;
    for (int e = 0; e < E_; ++e) {
      cp += (scnt[e] + 63) / 64 * 64;
      scum[e + 1] = cp;
    }
  }
  __syncthreads();

  if (c < 64) {
    // rank + scatter via wave64 ballot
    int j = tid;
    int e = sel[c * 256 + j];
    int w = j >> 6;
    int partial = 0;
    for (int i = 0; i < 2 * w; ++i) partial += hL[c * 8 + i][e];
    unsigned long long below = ((1ULL << (j & 63)) - 1ULL);
    int rank = 0;
#pragma unroll
    for (int ee = 0; ee < 8; ++ee) {
      unsigned long long m = __ballot(e == ee);
      if (ee == e) rank = __popcll(m & below);
    }
    int dst = scum[e] + preSC[c][e] + partial + rank;
    row_src[dst] = (c * 256 + j) >> 1;
  } else {
    // block 64: tile table, totals, padding fills
    if (tid == 0) {
      int nt = 0;
      for (int e = 0; e < E_; ++e) {
        int cnt = scnt[e];
        int cp = scum[e];
        int gs = scum[e + 1] - cp;
        int r = 0;
        while (r < gs) {
          int m = (gs - r >= 128) ? 128 : 64;
          int mv = cnt - r;
          if (mv < 0) mv = 0;
          if (mv > m) mv = m;
          tiles[nt++] = (cp + r) | (e << 15) | ((m == 128) ? (1 << 18) : 0) | (mv << 19);
          r += m;
        }
      }
      totals[0] = scum[8];
      totals[1] = nt;
    }
    for (int e = 0; e < E_; ++e) {
      int s = scum[e] + scnt[e], en = scum[e + 1];
      for (int i = s + tid; i < en; i += 256) row_src[i] = -1;
    }
    for (int i = scum[8] + tid; i < CAP_ + 64; i += 256) row_src[i] = -1;
  }
}

// ---------------- 3. grouped GEMM: m97 structure (128x128, BK=64, 32KiB, 4 waves) ----------------
#define READ_A(dst, KS)                                                         \
  {                                                                             \
    const unsigned short* p_ = As + (wr * 64 + lane15) * 64;                    \
    int co_ = (((KS) * 64 + g16) ^ swz) >> 1;                                   \
    _Pragma("unroll") for (int mi = 0; mi < 4; ++mi)                            \
      dst[mi] = *(const bf16x8*)(p_ + mi * 1024 + co_);                         \
  }

#define READ_B(dst, KS)                                                         \
  {                                                                             \
    const unsigned short* p_ = Bs + (wc * 64 + lane15) * 64;                    \
    int co_ = (((KS) * 64 + g16) ^ swz) >> 1;                                   \
    _Pragma("unroll") for (int ni = 0; ni < 4; ++ni)                            \
      dst[ni] = *(const bf16x8*)(p_ + ni * 1024 + co_);                         \
  }

#define MFMA16(AV, BV)                                                          \
  __builtin_amdgcn_s_setprio(1);                                                \
  _Pragma("unroll") for (int mi = 0; mi < 4; ++mi)                              \
    _Pragma("unroll") for (int ni = 0; ni < 4; ++ni)                            \
      acc[mi][ni] = __builtin_amdgcn_mfma_f32_16x16x32_bf16(                    \
          AV[mi], BV[ni], acc[mi][ni], 0, 0, 0);                                \
  __builtin_amdgcn_s_setprio(0);

__global__ __launch_bounds__(256, 5) void k_gemm(const unsigned short* __restrict__ xbf,
                                                 const unsigned short* __restrict__ w1t,
                                                 const int* __restrict__ row_src,
                                                 const int* __restrict__ tiles,
                                                 const int* __restrict__ totals,
                                                 float* __restrict__ out) {
  // T1: bijective XCD chunking; mtile-major inside a chunk.
  int P = blockIdx.y * MAXT_ + blockIdx.x;
  int L = (P & 7) * (MAXT_ * 16 / 8) + (P >> 3);
  int mtile = L >> 4, ny = L & 15;
  if (mtile >= totals[1]) return;

  int info = tiles[mtile];
  int rowBase = info & 0x7FFF;
  int e = (info >> 15) & 7;
  int mLimit = ((info >> 18) & 1) ? 128 : 64;
  int mValid = (info >> 19) & 0x1FF;

  __shared__ unsigned short As[128 * 64];
  __shared__ unsigned short Bs[128 * 64];

  int tid = threadIdx.x, wave = tid >> 6, lane = tid & 63;
  int lane15 = lane & 15;
  int g16 = (lane >> 4) * 16;          // byte offset of k-group
  int swz = (lane15 & 7) << 4;         // read-side swizzle (bytes)
  int wr = wave >> 1, wc = wave & 1;

  // staging geometry: 8 lanes/row, 16B each; inverse-swizzled source column
  int rr = tid >> 3;                           // 0..31 row within 32-row region
  int co = ((tid & 7) ^ (rr & 7)) << 3;        // elem offset (inverse swizzle)
  int woff = (tid >> 6) << 9;                  // wave*512 elems LDS dst offset

  // gathered A sources (one per 32-row region), clamped both ways
  const unsigned short* Asrc[4];
#pragma unroll
  for (int q = 0; q < 4; ++q) {
    int sr = row_src[rowBase + q * 32 + rr];
    if ((unsigned)sr >= (unsigned)T_) sr = 0;  // padding rows masked at epilogue
    Asrc[q] = xbf + (size_t)sr * D_ + co;
  }
  const unsigned short* Bg = w1t + ((size_t)e * DFFN_ + (size_t)ny * 128) * D_;

  f32x4 acc[4][4];
#pragma unroll
  for (int i = 0; i < 4; ++i)
#pragma unroll
    for (int j = 0; j < 4; ++j) acc[i][j] = (f32x4){0.f, 0.f, 0.f, 0.f};

  for (int t = 0; t < 16; ++t) {
    int k0 = t * 64;
#pragma unroll
    for (int q = 0; q < 4; ++q)
      __builtin_amdgcn_global_load_lds(
          (const __attribute__((address_space(1))) void*)(Asrc[q] + k0),
          (__attribute__((address_space(3))) void*)(As + q * 2048 + woff), 16, 0, 0);
#pragma unroll
    for (int q = 0; q < 4; ++q)
      __builtin_amdgcn_global_load_lds(
          (const __attribute__((address_space(1))) void*)(Bg + (size_t)(q * 32 + rr) * D_ + k0 + co),
          (__attribute__((address_space(3))) void*)(Bs + q * 2048 + woff), 16, 0, 0);
    __syncthreads();   // drains vmcnt+lgkm then barrier (m97 structure)

    bf16x8 a0[4], b0[4], a1[4], b1[4];
    READ_A(a0, 0);
    READ_B(b0, 0);
    MFMA16(a0, b0);
    READ_A(a1, 1);
    READ_B(b1, 1);
    MFMA16(a1, b1);
    __syncthreads();   // all waves done reading before next tile overwrites
  }

  // epilogue: C layout col=lane&15, row=(lane>>4)*4+q; mask padding rows to 0
#pragma unroll
  for (int mi = 0; mi < 4; ++mi) {
    int mrow = wr * 64 + mi * 16;
    if (mrow >= mLimit) continue;
    int rbase = mrow + (lane >> 4) * 4;
#pragma unroll
    for (int ni = 0; ni < 4; ++ni) {
      int col = ny * 128 + wc * 64 + ni * 16 + lane15;
      f32x4 v = acc[mi][ni];
#pragma unroll
      for (int q = 0; q < 4; ++q) {
        float val = (rbase + q < mValid) ? v[q] : 0.0f;
        out[(size_t)(rowBase + rbase + q) * DFFN_ + col] = val;
      }
    }
  }
}

extern "C" void kernel_launch(void* const* d_in, const int* in_sizes, int n_in,
                              void* d_out, int out_size, void* d_ws, size_t ws_size,
                              hipStream_t stream) {
  const float* x  = (const float*)d_in[0];
  const float* wr = (const float*)d_in[1];
  const float* w1 = (const float*)d_in[2];
  float* out = (float*)d_out;
  char* ws = (char*)d_ws;

  int* sel     = (int*)(ws + WS_SEL);
  int* totals  = (int*)(ws + WS_TOTALS);
  int* tiles   = (int*)(ws + WS_TILES);
  int* row_src = (int*)(ws + WS_ROWSRC);
  int* h       = (int*)(ws + WS_H);
  unsigned short* xbf = (unsigned short*)(ws + WS_XBF);
  unsigned short* w1t = (unsigned short*)(ws + WS_W1T);

  k_rw<<<1536, 256, 0, stream>>>(x, wr, w1, sel, h, xbf, w1t);
  k_place<<<577, 256, 0, stream>>>(sel, h, totals, tiles, row_src, out);
  k_gemm<<<dim3(MAXT_, 16), 256, 0, stream>>>(xbf, w1t, row_src, tiles, totals, out);
}

// Round 13
// 135.387 us; speedup vs baseline: 4.5362x; 4.5362x over previous
//
#include <hip/hip_runtime.h>
#include <stdint.h>

#define E_       8
#define D_       1024
#define DFFN_    2048
#define T_       8192
#define TK_      16384
#define CAP_     16896
#define MAXT_    144       // max 128-row tiles

// workspace layout (bytes)
#define WS_SEL      0u          // TK_*4
#define WS_TOTALS   0x10200u    // [0]=total_padded [1]=nTiles
#define WS_TILES    0x11300u    // MAXT_*4
#define WS_ROWSRC   0x12000u    // (CAP_+64)*4
#define WS_XBF      0x23000u    // T_*1024*2 = 16777216
#define WS_W1T      (0x23000u + 34603008u)              // 16384*1024*2 = 33554432
#define WS_H        (0x23000u + 34603008u + 33554432u)  // 512*8*4 router histograms

typedef __bf16 bf16x8 __attribute__((ext_vector_type(8)));
typedef float  f32x4  __attribute__((ext_vector_type(4)));
typedef unsigned short u16x8 __attribute__((ext_vector_type(8)));

__device__ __forceinline__ unsigned short f2bf(float f) {
  __bf16 b = (__bf16)f;                       // compiler RNE cast (single HW op)
  union { __bf16 h; unsigned short u; } v; v.h = b;
  return v.u;
}

// ---- 1. fused: router (0..511, + per-block histogram) + w1conv (512..1535) ----
__global__ __launch_bounds__(256) void k_rw(const float* __restrict__ x,
                                            const float* __restrict__ wr,
                                            const float* __restrict__ w1,
                                            int* __restrict__ sel,
                                            int* __restrict__ h,
                                            unsigned short* __restrict__ xbf,
                                            unsigned short* __restrict__ w1t) {
  __shared__ __align__(16) unsigned char smem[34816];  // max(router 32.9KB, w1conv 34KB)
  int tid = threadIdx.x;
  int bx = blockIdx.x;

  if (bx < 512) {
    // ---------- router: top-2 expert ids + bf16 cast of x + 32-entry histogram ----------
    float* lwr = (float*)smem;
    int* selL = (int*)(smem + 32768);    // 32 ints
    for (int i = tid; i < E_ * D_ / 4; i += 256)
      ((float4*)lwr)[i] = ((const float4*)wr)[i];
    __syncthreads();
    int wave = tid >> 6, lane = tid & 63;

    for (int tk = 0; tk < 4; ++tk) {
      int t = bx * 16 + wave * 4 + tk;
      double acc[E_];
#pragma unroll
      for (int e = 0; e < E_; ++e) acc[e] = 0.0;
      const float4* xr = (const float4*)(x + (size_t)t * D_);
      ushort4* xw = (ushort4*)(xbf + (size_t)t * D_);
#pragma unroll
      for (int j = 0; j < 4; ++j) {
        float4 v = xr[j * 64 + lane];
        ushort4 o;
        o.x = f2bf(v.x); o.y = f2bf(v.y); o.z = f2bf(v.z); o.w = f2bf(v.w);
        xw[j * 64 + lane] = o;
        int dbase = j * 256 + lane * 4;
#pragma unroll
        for (int e = 0; e < E_; ++e) {
          float4 w = *(const float4*)(lwr + e * D_ + dbase);
          acc[e] += (double)v.x * w.x + (double)v.y * w.y +
                    (double)v.z * w.z + (double)v.w * w.w;
        }
      }
#pragma unroll
      for (int e = 0; e < E_; ++e) {
        acc[e] += __shfl_xor(acc[e], 1, 64);
        acc[e] += __shfl_xor(acc[e], 2, 64);
        acc[e] += __shfl_xor(acc[e], 4, 64);
      }
      double s01 = (lane & 1) ? acc[1] : acc[0];
      double s23 = (lane & 1) ? acc[3] : acc[2];
      double s45 = (lane & 1) ? acc[5] : acc[4];
      double s67 = (lane & 1) ? acc[7] : acc[6];
      double t0 = (lane & 2) ? s23 : s01;
      double t1 = (lane & 2) ? s67 : s45;
      double u  = (lane & 4) ? t1 : t0;
      u += __shfl_xor(u, 8, 64);
      u += __shfl_xor(u, 16, 64);
      u += __shfl_xor(u, 32, 64);
      double lg[E_];
#pragma unroll
      for (int e = 0; e < E_; ++e) lg[e] = __shfl(u, e, 64);
      int e1 = 0; double b1 = lg[0];
#pragma unroll
      for (int e = 1; e < E_; ++e) if (lg[e] > b1) { b1 = lg[e]; e1 = e; }
      int e2 = (e1 == 0) ? 1 : 0; double b2 = lg[e2];
#pragma unroll
      for (int e = 0; e < E_; ++e) if (e != e1 && lg[e] > b2) { b2 = lg[e]; e2 = e; }
      if (lane == 0) {
        sel[2 * t]     = e1;
        sel[2 * t + 1] = e2;
        selL[wave * 8 + tk * 2]     = e1;
        selL[wave * 8 + tk * 2 + 1] = e2;
      }
    }
    __syncthreads();
    if (tid < E_) {
      int c = 0;
#pragma unroll
      for (int i = 0; i < 32; ++i) c += (selL[i] == tid);
      h[bx * E_ + tid] = c;
    }
  } else {
    // ---------- w1conv: 128d x 128n tile; 512B-contig reads, 256B-contig b128 writes ----------
    typedef unsigned short row136[136];
    row136* lds = (row136*)smem;
    int b = bx - 512;
    int n0 = (b & 127) * 128, d0 = (b >> 7) * 128;
    int rIn = tid >> 5, c4 = (tid & 31) * 4;
#pragma unroll
    for (int p = 0; p < 16; ++p) {
      int d = p * 8 + rIn;
      float4 v = *(const float4*)(w1 + (size_t)(d0 + d) * 16384 + n0 + c4);
      lds[d][c4 + 0] = f2bf(v.x);
      lds[d][c4 + 1] = f2bf(v.y);
      lds[d][c4 + 2] = f2bf(v.z);
      lds[d][c4 + 3] = f2bf(v.w);
    }
    __syncthreads();
    int nn = tid >> 3, d16 = (tid & 7) * 16;
#pragma unroll
    for (int q = 0; q < 4; ++q) {
      int n = q * 32 + nn;
      u16x8 o0, o1;
#pragma unroll
      for (int i = 0; i < 8; ++i) o0[i] = lds[d16 + i][n];
#pragma unroll
      for (int i = 0; i < 8; ++i) o1[i] = lds[d16 + 8 + i][n];
      unsigned short* dst = w1t + (size_t)(n0 + n) * 1024 + d0 + d16;
      *(u16x8*)dst = o0;
      *(u16x8*)(dst + 8) = o1;
    }
  }
}

// ---- 2. parallel placement (0..63 rank, 64 tile-table) + out-tail zero (65..576) ----
// tile word: bits0-14 rowBase | bits15-17 e | bit18 is128 | bits19-27 mValid
__global__ __launch_bounds__(256) void k_place(const int* __restrict__ sel,
                                               const int* __restrict__ h,
                                               int* __restrict__ totals,
                                               int* __restrict__ tiles,
                                               int* __restrict__ row_src,
                                               float* __restrict__ out) {
  int tid = threadIdx.x;
  int c = blockIdx.x;

  if (c >= 65) {
    // zero out rows [TK_, CAP_): gemm (launched after) overwrites valid ones
    int row = TK_ + (c - 65);
    float4 z = {0.f, 0.f, 0.f, 0.f};
    float4* o = (float4*)(out + (size_t)row * DFFN_);
    o[tid] = z;
    o[tid + 256] = z;
    return;
  }

  __shared__ int hL[512][8];     // router-block histograms
  __shared__ int preSC[64][8];   // exclusive prefix of 8-rb super-chunks per expert
  __shared__ int scnt[8];
  __shared__ int scum[9];

  // load h (16KB, coalesced)
  for (int i = tid; i < 512 * 8 / 4; i += 256)
    ((int4*)&hL[0][0])[i] = ((const int4*)h)[i];
  __syncthreads();

  // super-chunk sums
  for (int idx = tid; idx < 512; idx += 256) {
    int sc = idx >> 3, e = idx & 7;
    int s = 0;
#pragma unroll
    for (int i = 0; i < 8; ++i) s += hL[sc * 8 + i][e];
    preSC[sc][e] = s;
  }
  __syncthreads();

  // exclusive prefix over 64 super-chunks, per expert
  if (tid < 8) {
    int run = 0;
    for (int sc = 0; sc < 64; ++sc) {
      int v = preSC[sc][tid];
      preSC[sc][tid] = run;
      run += v;
    }
    scnt[tid] = run;
  }
  __syncthreads();
  if (tid == 0) {
    int cp = 0;
    scum[0] = 0;
    for (int e = 0; e < E_; ++e) {
      cp += (scnt[e] + 63) / 64 * 64;
      scum[e + 1] = cp;
    }
  }
  __syncthreads();

  if (c < 64) {
    // rank + scatter via wave64 ballot
    int j = tid;
    int e = sel[c * 256 + j];
    int w = j >> 6;
    int partial = 0;
    for (int i = 0; i < 2 * w; ++i) partial += hL[c * 8 + i][e];
    unsigned long long below = ((1ULL << (j & 63)) - 1ULL);
    int rank = 0;
#pragma unroll
    for (int ee = 0; ee < 8; ++ee) {
      unsigned long long m = __ballot(e == ee);
      if (ee == e) rank = __popcll(m & below);
    }
    int dst = scum[e] + preSC[c][e] + partial + rank;
    row_src[dst] = (c * 256 + j) >> 1;
  } else {
    // block 64: tile table, totals, padding fills
    if (tid == 0) {
      int nt = 0;
      for (int e = 0; e < E_; ++e) {
        int cnt = scnt[e];
        int cp = scum[e];
        int gs = scum[e + 1] - cp;
        int r = 0;
        while (r < gs) {
          int m = (gs - r >= 128) ? 128 : 64;
          int mv = cnt - r;
          if (mv < 0) mv = 0;
          if (mv > m) mv = m;
          tiles[nt++] = (cp + r) | (e << 15) | ((m == 128) ? (1 << 18) : 0) | (mv << 19);
          r += m;
        }
      }
      totals[0] = scum[8];
      totals[1] = nt;
    }
    for (int e = 0; e < E_; ++e) {
      int s = scum[e] + scnt[e], en = scum[e + 1];
      for (int i = s + tid; i < en; i += 256) row_src[i] = -1;
    }
    for (int i = scum[8] + tid; i < CAP_ + 64; i += 256) row_src[i] = -1;
  }
}

// ---------------- 3. grouped GEMM: m97 structure (128x128, BK=64, 32KiB, 4 waves) ----------------
// __launch_bounds__(256,4): (256,5) forced VGPR 64->48 and SPILLED THE ACCUMULATORS
// (R12: WRITE_SIZE 134MB->1.45GB, 86->583us). 4 is the max safe occupancy request here.
#define READ_A(dst, KS)                                                         \
  {                                                                             \
    const unsigned short* p_ = As + (wr * 64 + lane15) * 64;                    \
    int co_ = (((KS) * 64 + g16) ^ swz) >> 1;                                   \
    _Pragma("unroll") for (int mi = 0; mi < 4; ++mi)                            \
      dst[mi] = *(const bf16x8*)(p_ + mi * 1024 + co_);                         \
  }

#define READ_B(dst, KS)                                                         \
  {                                                                             \
    const unsigned short* p_ = Bs + (wc * 64 + lane15) * 64;                    \
    int co_ = (((KS) * 64 + g16) ^ swz) >> 1;                                   \
    _Pragma("unroll") for (int ni = 0; ni < 4; ++ni)                            \
      dst[ni] = *(const bf16x8*)(p_ + ni * 1024 + co_);                         \
  }

#define MFMA16(AV, BV)                                                          \
  __builtin_amdgcn_s_setprio(1);                                                \
  _Pragma("unroll") for (int mi = 0; mi < 4; ++mi)                              \
    _Pragma("unroll") for (int ni = 0; ni < 4; ++ni)                            \
      acc[mi][ni] = __builtin_amdgcn_mfma_f32_16x16x32_bf16(                    \
          AV[mi], BV[ni], acc[mi][ni], 0, 0, 0);                                \
  __builtin_amdgcn_s_setprio(0);

__global__ __launch_bounds__(256, 4) void k_gemm(const unsigned short* __restrict__ xbf,
                                                 const unsigned short* __restrict__ w1t,
                                                 const int* __restrict__ row_src,
                                                 const int* __restrict__ tiles,
                                                 const int* __restrict__ totals,
                                                 float* __restrict__ out) {
  // T1: bijective XCD chunking; mtile-major inside a chunk.
  int P = blockIdx.y * MAXT_ + blockIdx.x;
  int L = (P & 7) * (MAXT_ * 16 / 8) + (P >> 3);
  int mtile = L >> 4, ny = L & 15;
  if (mtile >= totals[1]) return;

  int info = tiles[mtile];
  int rowBase = info & 0x7FFF;
  int e = (info >> 15) & 7;
  int mLimit = ((info >> 18) & 1) ? 128 : 64;
  int mValid = (info >> 19) & 0x1FF;

  __shared__ unsigned short As[128 * 64];
  __shared__ unsigned short Bs[128 * 64];

  int tid = threadIdx.x, wave = tid >> 6, lane = tid & 63;
  int lane15 = lane & 15;
  int g16 = (lane >> 4) * 16;          // byte offset of k-group
  int swz = (lane15 & 7) << 4;         // read-side swizzle (bytes)
  int wr = wave >> 1, wc = wave & 1;

  // staging geometry: 8 lanes/row, 16B each; inverse-swizzled source column
  int rr = tid >> 3;                           // 0..31 row within 32-row region
  int co = ((tid & 7) ^ (rr & 7)) << 3;        // elem offset (inverse swizzle)
  int woff = (tid >> 6) << 9;                  // wave*512 elems LDS dst offset

  // gathered A sources (one per 32-row region), clamped both ways
  const unsigned short* Asrc[4];
#pragma unroll
  for (int q = 0; q < 4; ++q) {
    int sr = row_src[rowBase + q * 32 + rr];
    if ((unsigned)sr >= (unsigned)T_) sr = 0;  // padding rows masked at epilogue
    Asrc[q] = xbf + (size_t)sr * D_ + co;
  }
  const unsigned short* Bg = w1t + ((size_t)e * DFFN_ + (size_t)ny * 128) * D_;

  f32x4 acc[4][4];
#pragma unroll
  for (int i = 0; i < 4; ++i)
#pragma unroll
    for (int j = 0; j < 4; ++j) acc[i][j] = (f32x4){0.f, 0.f, 0.f, 0.f};

  for (int t = 0; t < 16; ++t) {
    int k0 = t * 64;
#pragma unroll
    for (int q = 0; q < 4; ++q)
      __builtin_amdgcn_global_load_lds(
          (const __attribute__((address_space(1))) void*)(Asrc[q] + k0),
          (__attribute__((address_space(3))) void*)(As + q * 2048 + woff), 16, 0, 0);
#pragma unroll
    for (int q = 0; q < 4; ++q)
      __builtin_amdgcn_global_load_lds(
          (const __attribute__((address_space(1))) void*)(Bg + (size_t)(q * 32 + rr) * D_ + k0 + co),
          (__attribute__((address_space(3))) void*)(Bs + q * 2048 + woff), 16, 0, 0);
    __syncthreads();   // drains vmcnt+lgkm then barrier (m97 structure)

    bf16x8 a0[4], b0[4], a1[4], b1[4];
    READ_A(a0, 0);
    READ_B(b0, 0);
    MFMA16(a0, b0);
    READ_A(a1, 1);
    READ_B(b1, 1);
    MFMA16(a1, b1);
    __syncthreads();   // all waves done reading before next tile overwrites
  }

  // epilogue: C layout col=lane&15, row=(lane>>4)*4+q; mask padding rows to 0
#pragma unroll
  for (int mi = 0; mi < 4; ++mi) {
    int mrow = wr * 64 + mi * 16;
    if (mrow >= mLimit) continue;
    int rbase = mrow + (lane >> 4) * 4;
#pragma unroll
    for (int ni = 0; ni < 4; ++ni) {
      int col = ny * 128 + wc * 64 + ni * 16 + lane15;
      f32x4 v = acc[mi][ni];
#pragma unroll
      for (int q = 0; q < 4; ++q) {
        float val = (rbase + q < mValid) ? v[q] : 0.0f;
        out[(size_t)(rowBase + rbase + q) * DFFN_ + col] = val;
      }
    }
  }
}

extern "C" void kernel_launch(void* const* d_in, const int* in_sizes, int n_in,
                              void* d_out, int out_size, void* d_ws, size_t ws_size,
                              hipStream_t stream) {
  const float* x  = (const float*)d_in[0];
  const float* wr = (const float*)d_in[1];
  const float* w1 = (const float*)d_in[2];
  float* out = (float*)d_out;
  char* ws = (char*)d_ws;

  int* sel     = (int*)(ws + WS_SEL);
  int* totals  = (int*)(ws + WS_TOTALS);
  int* tiles   = (int*)(ws + WS_TILES);
  int* row_src = (int*)(ws + WS_ROWSRC);
  int* h       = (int*)(ws + WS_H);
  unsigned short* xbf = (unsigned short*)(ws + WS_XBF);
  unsigned short* w1t = (unsigned short*)(ws + WS_W1T);

  k_rw<<<1536, 256, 0, stream>>>(x, wr, w1, sel, h, xbf, w1t);
  k_place<<<577, 256, 0, stream>>>(sel, h, totals, tiles, row_src, out);
  k_gemm<<<dim3(MAXT_, 16), 256, 0, stream>>>(xbf, w1t, row_src, tiles, totals, out);
}

// Round 14
// 133.209 us; speedup vs baseline: 4.6104x; 1.0164x over previous
//
#include <hip/hip_runtime.h>
#include <stdint.h>

#define E_       8
#define D_       1024
#define DFFN_    2048
#define T_       8192
#define TK_      16384
#define CAP_     16896
#define MAXT_    144       // max 128-row tiles

// workspace layout (bytes)
#define WS_SEL      0u          // TK_*4
#define WS_TOTALS   0x10200u    // [0]=total_padded [1]=nTiles
#define WS_TILES    0x11300u    // MAXT_*4
#define WS_ROWSRC   0x12000u    // (CAP_+64)*4
#define WS_XBF      0x23000u    // T_*1024*2 = 16777216
#define WS_W1T      (0x23000u + 34603008u)              // 16384*1024*2 = 33554432
#define WS_H        (0x23000u + 34603008u + 33554432u)  // 512*8*4 router histograms

typedef __bf16 bf16x8 __attribute__((ext_vector_type(8)));
typedef float  f32x4  __attribute__((ext_vector_type(4)));

__device__ __forceinline__ unsigned short f2bf(float f) {
  __bf16 b = (__bf16)f;                       // compiler RNE cast (single HW op)
  union { __bf16 h; unsigned short u; } v; v.h = b;
  return v.u;
}

// ---- 1. fused: router (0..511, + histogram) + w1conv (512..1535) + tail zero (1536..2047) ----
// w1conv uses the 64x256 row-258 transpose (measured conflict-free; the 128x128/row-136
// variant has an 8-way read conflict: 16-row stride = 1088 dwords ≡ 0 mod 32 — R13 regression).
__global__ __launch_bounds__(256) void k_rw(const float* __restrict__ x,
                                            const float* __restrict__ wr,
                                            const float* __restrict__ w1,
                                            int* __restrict__ sel,
                                            int* __restrict__ h,
                                            unsigned short* __restrict__ xbf,
                                            unsigned short* __restrict__ w1t,
                                            float* __restrict__ out) {
  __shared__ __align__(16) unsigned char smem[33024];
  int tid = threadIdx.x;
  int bx = blockIdx.x;

  if (bx >= 1536) {
    // zero out rows [TK_, CAP_): gemm (launched after) overwrites valid ones
    int row = TK_ + (bx - 1536);
    float4 z = {0.f, 0.f, 0.f, 0.f};
    float4* o = (float4*)(out + (size_t)row * DFFN_);
    o[tid] = z;
    o[tid + 256] = z;
    return;
  }

  if (bx < 512) {
    // ---------- router: top-2 expert ids + bf16 cast of x + 32-entry histogram ----------
    float* lwr = (float*)smem;
    int* selL = (int*)(smem + 32768);    // 32 ints
    for (int i = tid; i < E_ * D_ / 4; i += 256)
      ((float4*)lwr)[i] = ((const float4*)wr)[i];
    __syncthreads();
    int wave = tid >> 6, lane = tid & 63;

    for (int tk = 0; tk < 4; ++tk) {
      int t = bx * 16 + wave * 4 + tk;
      double acc[E_];
#pragma unroll
      for (int e = 0; e < E_; ++e) acc[e] = 0.0;
      const float4* xr = (const float4*)(x + (size_t)t * D_);
      ushort4* xw = (ushort4*)(xbf + (size_t)t * D_);
#pragma unroll
      for (int j = 0; j < 4; ++j) {
        float4 v = xr[j * 64 + lane];
        ushort4 o;
        o.x = f2bf(v.x); o.y = f2bf(v.y); o.z = f2bf(v.z); o.w = f2bf(v.w);
        xw[j * 64 + lane] = o;
        int dbase = j * 256 + lane * 4;
#pragma unroll
        for (int e = 0; e < E_; ++e) {
          float4 w = *(const float4*)(lwr + e * D_ + dbase);
          acc[e] += (double)v.x * w.x + (double)v.y * w.y +
                    (double)v.z * w.z + (double)v.w * w.w;
        }
      }
#pragma unroll
      for (int e = 0; e < E_; ++e) {
        acc[e] += __shfl_xor(acc[e], 1, 64);
        acc[e] += __shfl_xor(acc[e], 2, 64);
        acc[e] += __shfl_xor(acc[e], 4, 64);
      }
      double s01 = (lane & 1) ? acc[1] : acc[0];
      double s23 = (lane & 1) ? acc[3] : acc[2];
      double s45 = (lane & 1) ? acc[5] : acc[4];
      double s67 = (lane & 1) ? acc[7] : acc[6];
      double t0 = (lane & 2) ? s23 : s01;
      double t1 = (lane & 2) ? s67 : s45;
      double u  = (lane & 4) ? t1 : t0;
      u += __shfl_xor(u, 8, 64);
      u += __shfl_xor(u, 16, 64);
      u += __shfl_xor(u, 32, 64);
      double lg[E_];
#pragma unroll
      for (int e = 0; e < E_; ++e) lg[e] = __shfl(u, e, 64);
      int e1 = 0; double b1 = lg[0];
#pragma unroll
      for (int e = 1; e < E_; ++e) if (lg[e] > b1) { b1 = lg[e]; e1 = e; }
      int e2 = (e1 == 0) ? 1 : 0; double b2 = lg[e2];
#pragma unroll
      for (int e = 0; e < E_; ++e) if (e != e1 && lg[e] > b2) { b2 = lg[e]; e2 = e; }
      if (lane == 0) {
        sel[2 * t]     = e1;
        sel[2 * t + 1] = e2;
        selL[wave * 8 + tk * 2]     = e1;
        selL[wave * 8 + tk * 2 + 1] = e2;
      }
    }
    __syncthreads();
    if (tid < E_) {
      int c = 0;
#pragma unroll
      for (int i = 0; i < 32; ++i) c += (selL[i] == tid);
      h[bx * E_ + tid] = c;
    }
  } else {
    // ---------- w1conv: w1 [d][16384] f32 -> w1t [n][1024] bf16 (64x256 tile) ----------
    typedef unsigned short row258[258];
    row258* lds = (row258*)smem;
    int b = bx - 512;
    int n0 = (b & 63) * 256, d0 = (b >> 6) * 64;
    int rIn = tid >> 6, c4 = tid & 63;
#pragma unroll
    for (int p = 0; p < 16; ++p) {
      int row = p * 4 + rIn;
      float4 v = *(const float4*)(w1 + (size_t)(d0 + row) * 16384 + n0 + c4 * 4);
      lds[row][c4 * 4 + 0] = f2bf(v.x);
      lds[row][c4 * 4 + 1] = f2bf(v.y);
      lds[row][c4 * 4 + 2] = f2bf(v.z);
      lds[row][c4 * 4 + 3] = f2bf(v.w);
    }
    __syncthreads();
    int d2 = (tid & 15) * 4, nn = tid >> 4;
#pragma unroll
    for (int q = 0; q < 16; ++q) {
      int n = q * 16 + nn;
      ushort4 o;
      o.x = lds[d2 + 0][n]; o.y = lds[d2 + 1][n];
      o.z = lds[d2 + 2][n]; o.w = lds[d2 + 3][n];
      *(ushort4*)(w1t + (size_t)(n0 + n) * 1024 + d0 + d2) = o;
    }
  }
}

// ---- 2. parallel placement: 65 blocks. 0..63 rank+scatter via wave64 ballot;
//         block 64 writes tile table + padding. No atomics, disjoint writes.
// tile word: bits0-14 rowBase | bits15-17 e | bit18 is128 | bits19-27 mValid
__global__ __launch_bounds__(256) void k_place(const int* __restrict__ sel,
                                               const int* __restrict__ h,
                                               int* __restrict__ totals,
                                               int* __restrict__ tiles,
                                               int* __restrict__ row_src) {
  __shared__ int hL[512][8];     // router-block histograms
  __shared__ int preSC[64][8];   // exclusive prefix of 8-rb super-chunks per expert
  __shared__ int scnt[8];
  __shared__ int scum[9];
  int tid = threadIdx.x;
  int c = blockIdx.x;

  // load h (16KB, coalesced)
  for (int i = tid; i < 512 * 8 / 4; i += 256)
    ((int4*)&hL[0][0])[i] = ((const int4*)h)[i];
  __syncthreads();

  // super-chunk sums
  for (int idx = tid; idx < 512; idx += 256) {
    int sc = idx >> 3, e = idx & 7;
    int s = 0;
#pragma unroll
    for (int i = 0; i < 8; ++i) s += hL[sc * 8 + i][e];
    preSC[sc][e] = s;
  }
  __syncthreads();

  // exclusive prefix over 64 super-chunks, per expert
  if (tid < 8) {
    int run = 0;
    for (int sc = 0; sc < 64; ++sc) {
      int v = preSC[sc][tid];
      preSC[sc][tid] = run;
      run += v;
    }
    scnt[tid] = run;
  }
  __syncthreads();
  if (tid == 0) {
    int cp = 0;
    scum[0] = 0;
    for (int e = 0; e < E_; ++e) {
      cp += (scnt[e] + 63) / 64 * 64;
      scum[e + 1] = cp;
    }
  }
  __syncthreads();

  if (c < 64) {
    // rank + scatter: chunk c covers sel[c*256 .. c*256+255]
    int j = tid;
    int e = sel[c * 256 + j];
    int w = j >> 6;
    int partial = 0;
    for (int i = 0; i < 2 * w; ++i) partial += hL[c * 8 + i][e];
    unsigned long long below = ((1ULL << (j & 63)) - 1ULL);
    int rank = 0;
#pragma unroll
    for (int ee = 0; ee < 8; ++ee) {
      unsigned long long m = __ballot(e == ee);
      if (ee == e) rank = __popcll(m & below);
    }
    int dst = scum[e] + preSC[c][e] + partial + rank;
    row_src[dst] = (c * 256 + j) >> 1;
  } else {
    // block 64: tile table, totals, padding fills
    if (tid == 0) {
      int nt = 0;
      for (int e = 0; e < E_; ++e) {
        int cnt = scnt[e];
        int cp = scum[e];
        int gs = scum[e + 1] - cp;
        int r = 0;
        while (r < gs) {
          int m = (gs - r >= 128) ? 128 : 64;
          int mv = cnt - r;
          if (mv < 0) mv = 0;
          if (mv > m) mv = m;
          tiles[nt++] = (cp + r) | (e << 15) | ((m == 128) ? (1 << 18) : 0) | (mv << 19);
          r += m;
        }
      }
      totals[0] = scum[8];
      totals[1] = nt;
    }
    for (int e = 0; e < E_; ++e) {
      int s = scum[e] + scnt[e], en = scum[e + 1];
      for (int i = s + tid; i < en; i += 256) row_src[i] = -1;
    }
    for (int i = scum[8] + tid; i < CAP_ + 64; i += 256) row_src[i] = -1;
  }
}

// ---------------- 3. grouped GEMM: m97 structure (128x128, BK=64, 32KiB, 4 waves) ----------------
// __launch_bounds__(256,4): (256,5) forced VGPR 64->48 and SPILLED THE ACCUMULATORS
// (R12: WRITE_SIZE 134MB->1.45GB, 86->583us). 4 is the max safe occupancy request here.
#define READ_A(dst, KS)                                                         \
  {                                                                             \
    const unsigned short* p_ = As + (wr * 64 + lane15) * 64;                    \
    int co_ = (((KS) * 64 + g16) ^ swz) >> 1;                                   \
    _Pragma("unroll") for (int mi = 0; mi < 4; ++mi)                            \
      dst[mi] = *(const bf16x8*)(p_ + mi * 1024 + co_);                         \
  }

#define READ_B(dst, KS)                                                         \
  {                                                                             \
    const unsigned short* p_ = Bs + (wc * 64 + lane15) * 64;                    \
    int co_ = (((KS) * 64 + g16) ^ swz) >> 1;                                   \
    _Pragma("unroll") for (int ni = 0; ni < 4; ++ni)                            \
      dst[ni] = *(const bf16x8*)(p_ + ni * 1024 + co_);                         \
  }

#define MFMA16(AV, BV)                                                          \
  __builtin_amdgcn_s_setprio(1);                                                \
  _Pragma("unroll") for (int mi = 0; mi < 4; ++mi)                              \
    _Pragma("unroll") for (int ni = 0; ni < 4; ++ni)                            \
      acc[mi][ni] = __builtin_amdgcn_mfma_f32_16x16x32_bf16(                    \
          AV[mi], BV[ni], acc[mi][ni], 0, 0, 0);                                \
  __builtin_amdgcn_s_setprio(0);

__global__ __launch_bounds__(256, 4) void k_gemm(const unsigned short* __restrict__ xbf,
                                                 const unsigned short* __restrict__ w1t,
                                                 const int* __restrict__ row_src,
                                                 const int* __restrict__ tiles,
                                                 const int* __restrict__ totals,
                                                 float* __restrict__ out) {
  // T1: bijective XCD chunking; mtile-major inside a chunk.
  int P = blockIdx.y * MAXT_ + blockIdx.x;
  int L = (P & 7) * (MAXT_ * 16 / 8) + (P >> 3);
  int mtile = L >> 4, ny = L & 15;
  if (mtile >= totals[1]) return;

  int info = tiles[mtile];
  int rowBase = info & 0x7FFF;
  int e = (info >> 15) & 7;
  int mLimit = ((info >> 18) & 1) ? 128 : 64;
  int mValid = (info >> 19) & 0x1FF;

  __shared__ unsigned short As[128 * 64];
  __shared__ unsigned short Bs[128 * 64];

  int tid = threadIdx.x, wave = tid >> 6, lane = tid & 63;
  int lane15 = lane & 15;
  int g16 = (lane >> 4) * 16;          // byte offset of k-group
  int swz = (lane15 & 7) << 4;         // read-side swizzle (bytes)
  int wr = wave >> 1, wc = wave & 1;

  // staging geometry: 8 lanes/row, 16B each; inverse-swizzled source column
  int rr = tid >> 3;                           // 0..31 row within 32-row region
  int co = ((tid & 7) ^ (rr & 7)) << 3;        // elem offset (inverse swizzle)
  int woff = (tid >> 6) << 9;                  // wave*512 elems LDS dst offset

  // gathered A sources (one per 32-row region), clamped both ways
  const unsigned short* Asrc[4];
#pragma unroll
  for (int q = 0; q < 4; ++q) {
    int sr = row_src[rowBase + q * 32 + rr];
    if ((unsigned)sr >= (unsigned)T_) sr = 0;  // padding rows masked at epilogue
    Asrc[q] = xbf + (size_t)sr * D_ + co;
  }
  const unsigned short* Bg = w1t + ((size_t)e * DFFN_ + (size_t)ny * 128) * D_;

  f32x4 acc[4][4];
#pragma unroll
  for (int i = 0; i < 4; ++i)
#pragma unroll
    for (int j = 0; j < 4; ++j) acc[i][j] = (f32x4){0.f, 0.f, 0.f, 0.f};

  for (int t = 0; t < 16; ++t) {
    int k0 = t * 64;
#pragma unroll
    for (int q = 0; q < 4; ++q)
      __builtin_amdgcn_global_load_lds(
          (const __attribute__((address_space(1))) void*)(Asrc[q] + k0),
          (__attribute__((address_space(3))) void*)(As + q * 2048 + woff), 16, 0, 0);
#pragma unroll
    for (int q = 0; q < 4; ++q)
      __builtin_amdgcn_global_load_lds(
          (const __attribute__((address_space(1))) void*)(Bg + (size_t)(q * 32 + rr) * D_ + k0 + co),
          (__attribute__((address_space(3))) void*)(Bs + q * 2048 + woff), 16, 0, 0);
    __syncthreads();   // drains vmcnt+lgkm then barrier (m97 structure)

    bf16x8 a0[4], b0[4], a1[4], b1[4];
    READ_A(a0, 0);
    READ_B(b0, 0);
    MFMA16(a0, b0);
    READ_A(a1, 1);
    READ_B(b1, 1);
    MFMA16(a1, b1);
    __syncthreads();   // all waves done reading before next tile overwrites
  }

  // epilogue: C layout col=lane&15, row=(lane>>4)*4+q; mask padding rows to 0
#pragma unroll
  for (int mi = 0; mi < 4; ++mi) {
    int mrow = wr * 64 + mi * 16;
    if (mrow >= mLimit) continue;
    int rbase = mrow + (lane >> 4) * 4;
#pragma unroll
    for (int ni = 0; ni < 4; ++ni) {
      int col = ny * 128 + wc * 64 + ni * 16 + lane15;
      f32x4 v = acc[mi][ni];
#pragma unroll
      for (int q = 0; q < 4; ++q) {
        float val = (rbase + q < mValid) ? v[q] : 0.0f;
        out[(size_t)(rowBase + rbase + q) * DFFN_ + col] = val;
      }
    }
  }
}

extern "C" void kernel_launch(void* const* d_in, const int* in_sizes, int n_in,
                              void* d_out, int out_size, void* d_ws, size_t ws_size,
                              hipStream_t stream) {
  const float* x  = (const float*)d_in[0];
  const float* wr = (const float*)d_in[1];
  const float* w1 = (const float*)d_in[2];
  float* out = (float*)d_out;
  char* ws = (char*)d_ws;

  int* sel     = (int*)(ws + WS_SEL);
  int* totals  = (int*)(ws + WS_TOTALS);
  int* tiles   = (int*)(ws + WS_TILES);
  int* row_src = (int*)(ws + WS_ROWSRC);
  int* h       = (int*)(ws + WS_H);
  unsigned short* xbf = (unsigned short*)(ws + WS_XBF);
  unsigned short* w1t = (unsigned short*)(ws + WS_W1T);

  k_rw<<<2048, 256, 0, stream>>>(x, wr, w1, sel, h, xbf, w1t, out);
  k_place<<<65, 256, 0, stream>>>(sel, h, totals, tiles, row_src);
  k_gemm<<<dim3(MAXT_, 16), 256, 0, stream>>>(xbf, w1t, row_src, tiles, totals, out);
}

// Round 15
// 126.655 us; speedup vs baseline: 4.8489x; 1.0517x over previous
//
#include <hip/hip_runtime.h>
#include <stdint.h>

#define E_       8
#define D_       1024
#define DFFN_    2048
#define T_       8192
#define TK_      16384
#define CAP_     16896
#define MAXT_    144       // max 128-row tiles

// workspace layout (bytes)
#define WS_SEL      0u          // TK_*4
#define WS_TOTALS   0x10200u    // [0]=total_padded [1]=nTiles
#define WS_TILES    0x11300u    // MAXT_*4
#define WS_ROWSRC   0x12000u    // (CAP_+64)*4
#define WS_XBF      0x23000u    // T_*1024*2 = 16777216
#define WS_W1T      (0x23000u + 34603008u)              // 16384*1024*2 = 33554432
#define WS_H        (0x23000u + 34603008u + 33554432u)  // 512*8*4 router histograms

typedef __bf16 bf16x8 __attribute__((ext_vector_type(8)));
typedef float  f32x4  __attribute__((ext_vector_type(4)));

// Hand-rolled RNE f32->bf16. MEASURED FASTER than native (__bf16) cast:
// R11 (this) 126.6us vs R14 (native cast, otherwise identical) 133.2us.
__device__ __forceinline__ unsigned short f2bf(float f) {
  union { float f; uint32_t u; } v; v.f = f;
  return (unsigned short)((v.u + 0x7fffu + ((v.u >> 16) & 1u)) >> 16);
}

// ---- 1. fused: router (0..511, + histogram) + w1conv (512..1535) + tail zero (1536..2047) ----
// w1conv uses the 64x256 row-258 transpose (conflict-free: stride 516 ≡ 4 mod 32; the
// 128x128/row-136 variant has an 8-way read conflict — R13 regression).
__global__ __launch_bounds__(256) void k_rw(const float* __restrict__ x,
                                            const float* __restrict__ wr,
                                            const float* __restrict__ w1,
                                            int* __restrict__ sel,
                                            int* __restrict__ h,
                                            unsigned short* __restrict__ xbf,
                                            unsigned short* __restrict__ w1t,
                                            float* __restrict__ out) {
  __shared__ __align__(16) unsigned char smem[33024];
  int tid = threadIdx.x;
  int bx = blockIdx.x;

  if (bx >= 1536) {
    // zero out rows [TK_, CAP_): gemm (launched after) overwrites valid ones
    int row = TK_ + (bx - 1536);
    float4 z = {0.f, 0.f, 0.f, 0.f};
    float4* o = (float4*)(out + (size_t)row * DFFN_);
    o[tid] = z;
    o[tid + 256] = z;
    return;
  }

  if (bx < 512) {
    // ---------- router: top-2 expert ids + bf16 cast of x + 32-entry histogram ----------
    float* lwr = (float*)smem;
    int* selL = (int*)(smem + 32768);    // 32 ints
    for (int i = tid; i < E_ * D_ / 4; i += 256)
      ((float4*)lwr)[i] = ((const float4*)wr)[i];
    __syncthreads();
    int wave = tid >> 6, lane = tid & 63;

    for (int tk = 0; tk < 4; ++tk) {
      int t = bx * 16 + wave * 4 + tk;
      double acc[E_];
#pragma unroll
      for (int e = 0; e < E_; ++e) acc[e] = 0.0;
      const float4* xr = (const float4*)(x + (size_t)t * D_);
      ushort4* xw = (ushort4*)(xbf + (size_t)t * D_);
#pragma unroll
      for (int j = 0; j < 4; ++j) {
        float4 v = xr[j * 64 + lane];
        ushort4 o;
        o.x = f2bf(v.x); o.y = f2bf(v.y); o.z = f2bf(v.z); o.w = f2bf(v.w);
        xw[j * 64 + lane] = o;
        int dbase = j * 256 + lane * 4;
#pragma unroll
        for (int e = 0; e < E_; ++e) {
          float4 w = *(const float4*)(lwr + e * D_ + dbase);
          acc[e] += (double)v.x * w.x + (double)v.y * w.y +
                    (double)v.z * w.z + (double)v.w * w.w;
        }
      }
#pragma unroll
      for (int e = 0; e < E_; ++e) {
        acc[e] += __shfl_xor(acc[e], 1, 64);
        acc[e] += __shfl_xor(acc[e], 2, 64);
        acc[e] += __shfl_xor(acc[e], 4, 64);
      }
      double s01 = (lane & 1) ? acc[1] : acc[0];
      double s23 = (lane & 1) ? acc[3] : acc[2];
      double s45 = (lane & 1) ? acc[5] : acc[4];
      double s67 = (lane & 1) ? acc[7] : acc[6];
      double t0 = (lane & 2) ? s23 : s01;
      double t1 = (lane & 2) ? s67 : s45;
      double u  = (lane & 4) ? t1 : t0;
      u += __shfl_xor(u, 8, 64);
      u += __shfl_xor(u, 16, 64);
      u += __shfl_xor(u, 32, 64);
      double lg[E_];
#pragma unroll
      for (int e = 0; e < E_; ++e) lg[e] = __shfl(u, e, 64);
      int e1 = 0; double b1 = lg[0];
#pragma unroll
      for (int e = 1; e < E_; ++e) if (lg[e] > b1) { b1 = lg[e]; e1 = e; }
      int e2 = (e1 == 0) ? 1 : 0; double b2 = lg[e2];
#pragma unroll
      for (int e = 0; e < E_; ++e) if (e != e1 && lg[e] > b2) { b2 = lg[e]; e2 = e; }
      if (lane == 0) {
        sel[2 * t]     = e1;
        sel[2 * t + 1] = e2;
        selL[wave * 8 + tk * 2]     = e1;
        selL[wave * 8 + tk * 2 + 1] = e2;
      }
    }
    __syncthreads();
    if (tid < E_) {
      int c = 0;
#pragma unroll
      for (int i = 0; i < 32; ++i) c += (selL[i] == tid);
      h[bx * E_ + tid] = c;
    }
  } else {
    // ---------- w1conv: w1 [d][16384] f32 -> w1t [n][1024] bf16 (64x256 tile) ----------
    typedef unsigned short row258[258];
    row258* lds = (row258*)smem;
    int b = bx - 512;
    int n0 = (b & 63) * 256, d0 = (b >> 6) * 64;
    int rIn = tid >> 6, c4 = tid & 63;
#pragma unroll
    for (int p = 0; p < 16; ++p) {
      int row = p * 4 + rIn;
      float4 v = *(const float4*)(w1 + (size_t)(d0 + row) * 16384 + n0 + c4 * 4);
      lds[row][c4 * 4 + 0] = f2bf(v.x);
      lds[row][c4 * 4 + 1] = f2bf(v.y);
      lds[row][c4 * 4 + 2] = f2bf(v.z);
      lds[row][c4 * 4 + 3] = f2bf(v.w);
    }
    __syncthreads();
    int d2 = (tid & 15) * 4, nn = tid >> 4;
#pragma unroll
    for (int q = 0; q < 16; ++q) {
      int n = q * 16 + nn;
      ushort4 o;
      o.x = lds[d2 + 0][n]; o.y = lds[d2 + 1][n];
      o.z = lds[d2 + 2][n]; o.w = lds[d2 + 3][n];
      *(ushort4*)(w1t + (size_t)(n0 + n) * 1024 + d0 + d2) = o;
    }
  }
}

// ---- 2. parallel placement: 65 blocks. 0..63 rank+scatter via wave64 ballot;
//         block 64 writes tile table + padding. No atomics, disjoint writes.
// tile word: bits0-14 rowBase | bits15-17 e | bit18 is128 | bits19-27 mValid
__global__ __launch_bounds__(256) void k_place(const int* __restrict__ sel,
                                               const int* __restrict__ h,
                                               int* __restrict__ totals,
                                               int* __restrict__ tiles,
                                               int* __restrict__ row_src) {
  __shared__ int hL[512][8];     // router-block histograms
  __shared__ int preSC[64][8];   // exclusive prefix of 8-rb super-chunks per expert
  __shared__ int scnt[8];
  __shared__ int scum[9];
  int tid = threadIdx.x;
  int c = blockIdx.x;

  // load h (16KB, coalesced)
  for (int i = tid; i < 512 * 8 / 4; i += 256)
    ((int4*)&hL[0][0])[i] = ((const int4*)h)[i];
  __syncthreads();

  // super-chunk sums
  for (int idx = tid; idx < 512; idx += 256) {
    int sc = idx >> 3, e = idx & 7;
    int s = 0;
#pragma unroll
    for (int i = 0; i < 8; ++i) s += hL[sc * 8 + i][e];
    preSC[sc][e] = s;
  }
  __syncthreads();

  // exclusive prefix over 64 super-chunks, per expert
  if (tid < 8) {
    int run = 0;
    for (int sc = 0; sc < 64; ++sc) {
      int v = preSC[sc][tid];
      preSC[sc][tid] = run;
      run += v;
    }
    scnt[tid] = run;
  }
  __syncthreads();
  if (tid == 0) {
    int cp = 0;
    scum[0] = 0;
    for (int e = 0; e < E_; ++e) {
      cp += (scnt[e] + 63) / 64 * 64;
      scum[e + 1] = cp;
    }
  }
  __syncthreads();

  if (c < 64) {
    // rank + scatter: chunk c covers sel[c*256 .. c*256+255]
    int j = tid;
    int e = sel[c * 256 + j];
    int w = j >> 6;
    int partial = 0;
    for (int i = 0; i < 2 * w; ++i) partial += hL[c * 8 + i][e];
    unsigned long long below = ((1ULL << (j & 63)) - 1ULL);
    int rank = 0;
#pragma unroll
    for (int ee = 0; ee < 8; ++ee) {
      unsigned long long m = __ballot(e == ee);
      if (ee == e) rank = __popcll(m & below);
    }
    int dst = scum[e] + preSC[c][e] + partial + rank;
    row_src[dst] = (c * 256 + j) >> 1;
  } else {
    // block 64: tile table, totals, padding fills
    if (tid == 0) {
      int nt = 0;
      for (int e = 0; e < E_; ++e) {
        int cnt = scnt[e];
        int cp = scum[e];
        int gs = scum[e + 1] - cp;
        int r = 0;
        while (r < gs) {
          int m = (gs - r >= 128) ? 128 : 64;
          int mv = cnt - r;
          if (mv < 0) mv = 0;
          if (mv > m) mv = m;
          tiles[nt++] = (cp + r) | (e << 15) | ((m == 128) ? (1 << 18) : 0) | (mv << 19);
          r += m;
        }
      }
      totals[0] = scum[8];
      totals[1] = nt;
    }
    for (int e = 0; e < E_; ++e) {
      int s = scum[e] + scnt[e], en = scum[e + 1];
      for (int i = s + tid; i < en; i += 256) row_src[i] = -1;
    }
    for (int i = scum[8] + tid; i < CAP_ + 64; i += 256) row_src[i] = -1;
  }
}

// ---------------- 3. grouped GEMM: m97 structure (128x128, BK=64, 32KiB, 4 waves) ----------------
// __launch_bounds__(256,4): (256,5) forced VGPR 64->48 and SPILLED THE ACCUMULATORS
// (R12: WRITE_SIZE 134MB->1.45GB, 86->583us). 4 is the max safe occupancy request here.
#define READ_A(dst, KS)                                                         \
  {                                                                             \
    const unsigned short* p_ = As + (wr * 64 + lane15) * 64;                    \
    int co_ = (((KS) * 64 + g16) ^ swz) >> 1;                                   \
    _Pragma("unroll") for (int mi = 0; mi < 4; ++mi)                            \
      dst[mi] = *(const bf16x8*)(p_ + mi * 1024 + co_);                         \
  }

#define READ_B(dst, KS)                                                         \
  {                                                                             \
    const unsigned short* p_ = Bs + (wc * 64 + lane15) * 64;                    \
    int co_ = (((KS) * 64 + g16) ^ swz) >> 1;                                   \
    _Pragma("unroll") for (int ni = 0; ni < 4; ++ni)                            \
      dst[ni] = *(const bf16x8*)(p_ + ni * 1024 + co_);                         \
  }

#define MFMA16(AV, BV)                                                          \
  __builtin_amdgcn_s_setprio(1);                                                \
  _Pragma("unroll") for (int mi = 0; mi < 4; ++mi)                              \
    _Pragma("unroll") for (int ni = 0; ni < 4; ++ni)                            \
      acc[mi][ni] = __builtin_amdgcn_mfma_f32_16x16x32_bf16(                    \
          AV[mi], BV[ni], acc[mi][ni], 0, 0, 0);                                \
  __builtin_amdgcn_s_setprio(0);

__global__ __launch_bounds__(256, 4) void k_gemm(const unsigned short* __restrict__ xbf,
                                                 const unsigned short* __restrict__ w1t,
                                                 const int* __restrict__ row_src,
                                                 const int* __restrict__ tiles,
                                                 const int* __restrict__ totals,
                                                 float* __restrict__ out) {
  // T1: bijective XCD chunking; mtile-major inside a chunk.
  int P = blockIdx.y * MAXT_ + blockIdx.x;
  int L = (P & 7) * (MAXT_ * 16 / 8) + (P >> 3);
  int mtile = L >> 4, ny = L & 15;
  if (mtile >= totals[1]) return;

  int info = tiles[mtile];
  int rowBase = info & 0x7FFF;
  int e = (info >> 15) & 7;
  int mLimit = ((info >> 18) & 1) ? 128 : 64;
  int mValid = (info >> 19) & 0x1FF;

  __shared__ unsigned short As[128 * 64];
  __shared__ unsigned short Bs[128 * 64];

  int tid = threadIdx.x, wave = tid >> 6, lane = tid & 63;
  int lane15 = lane & 15;
  int g16 = (lane >> 4) * 16;          // byte offset of k-group
  int swz = (lane15 & 7) << 4;         // read-side swizzle (bytes)
  int wr = wave >> 1, wc = wave & 1;

  // staging geometry: 8 lanes/row, 16B each; inverse-swizzled source column
  int rr = tid >> 3;                           // 0..31 row within 32-row region
  int co = ((tid & 7) ^ (rr & 7)) << 3;        // elem offset (inverse swizzle)
  int woff = (tid >> 6) << 9;                  // wave*512 elems LDS dst offset

  // gathered A sources (one per 32-row region), clamped both ways
  const unsigned short* Asrc[4];
#pragma unroll
  for (int q = 0; q < 4; ++q) {
    int sr = row_src[rowBase + q * 32 + rr];
    if ((unsigned)sr >= (unsigned)T_) sr = 0;  // padding rows masked at epilogue
    Asrc[q] = xbf + (size_t)sr * D_ + co;
  }
  const unsigned short* Bg = w1t + ((size_t)e * DFFN_ + (size_t)ny * 128) * D_;

  f32x4 acc[4][4];
#pragma unroll
  for (int i = 0; i < 4; ++i)
#pragma unroll
    for (int j = 0; j < 4; ++j) acc[i][j] = (f32x4){0.f, 0.f, 0.f, 0.f};

  for (int t = 0; t < 16; ++t) {
    int k0 = t * 64;
#pragma unroll
    for (int q = 0; q < 4; ++q)
      __builtin_amdgcn_global_load_lds(
          (const __attribute__((address_space(1))) void*)(Asrc[q] + k0),
          (__attribute__((address_space(3))) void*)(As + q * 2048 + woff), 16, 0, 0);
#pragma unroll
    for (int q = 0; q < 4; ++q)
      __builtin_amdgcn_global_load_lds(
          (const __attribute__((address_space(1))) void*)(Bg + (size_t)(q * 32 + rr) * D_ + k0 + co),
          (__attribute__((address_space(3))) void*)(Bs + q * 2048 + woff), 16, 0, 0);
    __syncthreads();   // drains vmcnt+lgkm then barrier (m97 structure)

    bf16x8 a0[4], b0[4], a1[4], b1[4];
    READ_A(a0, 0);
    READ_B(b0, 0);
    MFMA16(a0, b0);
    READ_A(a1, 1);
    READ_B(b1, 1);
    MFMA16(a1, b1);
    __syncthreads();   // all waves done reading before next tile overwrites
  }

  // epilogue: C layout col=lane&15, row=(lane>>4)*4+q; mask padding rows to 0
#pragma unroll
  for (int mi = 0; mi < 4; ++mi) {
    int mrow = wr * 64 + mi * 16;
    if (mrow >= mLimit) continue;
    int rbase = mrow + (lane >> 4) * 4;
#pragma unroll
    for (int ni = 0; ni < 4; ++ni) {
      int col = ny * 128 + wc * 64 + ni * 16 + lane15;
      f32x4 v = acc[mi][ni];
#pragma unroll
      for (int q = 0; q < 4; ++q) {
        float val = (rbase + q < mValid) ? v[q] : 0.0f;
        out[(size_t)(rowBase + rbase + q) * DFFN_ + col] = val;
      }
    }
  }
}

extern "C" void kernel_launch(void* const* d_in, const int* in_sizes, int n_in,
                              void* d_out, int out_size, void* d_ws, size_t ws_size,
                              hipStream_t stream) {
  const float* x  = (const float*)d_in[0];
  const float* wr = (const float*)d_in[1];
  const float* w1 = (const float*)d_in[2];
  float* out = (float*)d_out;
  char* ws = (char*)d_ws;

  int* sel     = (int*)(ws + WS_SEL);
  int* totals  = (int*)(ws + WS_TOTALS);
  int* tiles   = (int*)(ws + WS_TILES);
  int* row_src = (int*)(ws + WS_ROWSRC);
  int* h       = (int*)(ws + WS_H);
  unsigned short* xbf = (unsigned short*)(ws + WS_XBF);
  unsigned short* w1t = (unsigned short*)(ws + WS_W1T);

  k_rw<<<2048, 256, 0, stream>>>(x, wr, w1, sel, h, xbf, w1t, out);
  k_place<<<65, 256, 0, stream>>>(sel, h, totals, tiles, row_src);
  k_gemm<<<dim3(MAXT_, 16), 256, 0, stream>>>(xbf, w1t, row_src, tiles, totals, out);
}